// Round 1
// baseline (107.992 us; speedup 1.0000x reference)
//
#include <hip/hip_runtime.h>
#include <hip/hip_fp8.h>

// GE2E loss, fp8-MFMA v5. input [N=1024][M=20][D=256] fp32 -> scalar.
//   prep (256 blocks, 4 speakers/block, 1 wave each): keeps all 20 rows in
//     regs; centroid c, cc=||c||^2, c_hat fp8 B-frags (unchanged layout);
//     NEW: exact fp32 uu/uc per row (64-lane butterfly), s=w*rsqrt(uu) folded
//     into fp8 A-frags written to global in the exact 32x32x16 fp8 A-frag
//     order (LDS transpose, stride-65 to kill bank conflicts). Writes
//     uuA/ucA/ccv for the epilogue. Zeroes out.
//   main (640 blocks, 4 waves, __launch_bounds__(256,3) -> 3 blk/CU):
//     NO staging phase: A-frags loaded straight from global (8 KB/block,
//     L2/L3-resident), B tiles ping-pong prefetched (fully unrolled, static
//     Ba/Bb reg sets -> no rotate copies, counted vmcnt) so L2 latency hides
//     under the previous tile's 16 MFMAs + exp chain. setprio(1) around the
//     MFMA cluster (independent waves, no barrier in loop). One atomicAdd
//     per block. Armor: exp clamped, rsqrt/log floored.

#define D_DIM 256
#define N_SPK 1024
#define M_UTT 20

typedef long lx2 __attribute__((ext_vector_type(2)));
typedef float f32x16 __attribute__((ext_vector_type(16)));

__device__ __forceinline__ int pk4_fp8(float x0, float x1, float x2, float x3) {
#if __has_builtin(__builtin_amdgcn_cvt_pk_fp8_f32)
  int v = __builtin_amdgcn_cvt_pk_fp8_f32(x0, x1, 0, false);
  v = __builtin_amdgcn_cvt_pk_fp8_f32(x2, x3, v, true);
  return v;
#else
  union { int i; unsigned char b[4]; } u;
  u.b[0] = __hip_fp8_e4m3(x0).__x;
  u.b[1] = __hip_fp8_e4m3(x1).__x;
  u.b[2] = __hip_fp8_e4m3(x2).__x;
  u.b[3] = __hip_fp8_e4m3(x3).__x;
  return u.i;
#endif
}

// ---------------- Kernel A: prep (1 wave per speaker) ----------------
// Produces: bsw (fp8 B-frags), Ag (fp8 A-frags, pre-swizzled), uuA, ucA, ccv.
__global__ __launch_bounds__(256) void ge2e_prep(
    const float* __restrict__ inp, const float* __restrict__ wp,
    unsigned int* __restrict__ bsw32, int4* __restrict__ Ag,
    float* __restrict__ uuA, float* __restrict__ ucA,
    float* __restrict__ ccv, float* __restrict__ out) {
  __shared__ unsigned int q8[4][M_UTT][65];  // stride 65: <=2-way bank alias
  const int tid = threadIdx.x, lane = tid & 63, wv = tid >> 6;
  const int s = blockIdx.x * 4 + wv;  // speaker; lane owns dims 4*lane..+3
  if (blockIdx.x == 0 && tid == 0) out[0] = 0.0f;

  const float4* up =
      reinterpret_cast<const float4*>(inp + (size_t)s * (M_UTT * D_DIM)) + lane;
  float4 uf[M_UTT];
  float4 a = make_float4(0.f, 0.f, 0.f, 0.f);
#pragma unroll
  for (int m = 0; m < M_UTT; ++m) {
    uf[m] = up[m * (D_DIM / 4)];
    a.x += uf[m].x; a.y += uf[m].y; a.z += uf[m].z; a.w += uf[m].w;
  }
  const float inv = 1.0f / (float)M_UTT;
  const float4 c = make_float4(a.x * inv, a.y * inv, a.z * inv, a.w * inv);

  float cc = c.x * c.x + c.y * c.y + c.z * c.z + c.w * c.w;
#pragma unroll
  for (int o = 1; o < 64; o <<= 1) cc += __shfl_xor(cc, o, 64);
  if (lane == 0) ccv[s] = cc;

  {  // B-frag: lane l holds B[n=l&31][k=(l>>5)*8+j]; mem [tile*8+p][64][16B].
    const float rc = rsqrtf(fmaxf(cc, 1e-20f));
    const int qb = pk4_fp8(c.x * rc, c.y * rc, c.z * rc, c.w * rc);
    const int t = s >> 5, n5 = s & 31;
    const int p = lane >> 3, sub = (lane >> 2) & 1;
    const int hf = (lane >> 1) & 1, jb = (lane & 1) * 4;
    bsw32[((((t * 8 + p) * 64) + hf * 32 + n5) * 16 + sub * 8 + jb) >> 2] =
        (unsigned int)qb;
  }

  // per-row exact fp32 uu/uc; fold s=w*rsqrt(uu) into fp8 quantization
  const float w = wp[0];
#pragma unroll
  for (int m = 0; m < M_UTT; ++m) {
    float uu = uf[m].x * uf[m].x + uf[m].y * uf[m].y + uf[m].z * uf[m].z +
               uf[m].w * uf[m].w;
    float uc = uf[m].x * c.x + uf[m].y * c.y + uf[m].z * c.z + uf[m].w * c.w;
#pragma unroll
    for (int o = 1; o < 64; o <<= 1) {
      uu += __shfl_xor(uu, o, 64);
      uc += __shfl_xor(uc, o, 64);
    }
    if (lane == 0) {
      uuA[s * M_UTT + m] = uu;
      ucA[s * M_UTT + m] = uc;
    }
    const float sm = w * rsqrtf(fmaxf(uu, 1e-20f));
    q8[wv][m][lane] =
        (unsigned int)pk4_fp8(sm * uf[m].x, sm * uf[m].y, sm * uf[m].z,
                              sm * uf[m].w);
  }
  __syncthreads();

  // transpose-out to A-frag order: int4 at Ag[(br*8+p)*64 + (r&31) + 32*hf]
  //   hf=0 (ch0): dims {32p+0-7, 32p+16-23} = prep lanes {8p,8p+1,8p+4,8p+5}
  //   hf=1 (ch1): dims {32p+8-15, 32p+24-31} = lanes {8p+2,8p+3,8p+6,8p+7}
  if (lane < 2 * M_UTT) {
    const int m = lane >> 1, hf = lane & 1;
    const int r = s * M_UTT + m;
    const int br = r >> 5, l2 = (r & 31) + 32 * hf;
#pragma unroll
    for (int p = 0; p < 8; ++p) {
      const int c0 = 8 * p + 2 * hf;
      int4 v;
      v.x = (int)q8[wv][m][c0];
      v.y = (int)q8[wv][m][c0 + 1];
      v.z = (int)q8[wv][m][c0 + 4];
      v.w = (int)q8[wv][m][c0 + 5];
      Ag[((size_t)(br * 8 + p)) * 64 + l2] = v;
    }
  }
}

// ---------------- Kernel B: fp8 MFMA GEMM + fused sumexp ----------------
__global__ __launch_bounds__(256, 3) void ge2e_main(
    const int4* __restrict__ Ag, const unsigned char* __restrict__ bsw,
    const float* __restrict__ wp, const float* __restrict__ uuA,
    const float* __restrict__ ucA, const float* __restrict__ ccv,
    float* __restrict__ out) {
  __shared__ float rowtot[4][32];
  const int tid = threadIdx.x, lane = tid & 63, wv = tid >> 6, hl = lane >> 5;

  lx2 A[8];
  const lx2* Agv = reinterpret_cast<const lx2*>(Ag);
#pragma unroll
  for (int p = 0; p < 8; ++p)
    A[p] = Agv[((size_t)blockIdx.x * 8 + p) * 64 + lane];

  float sume[16];
#pragma unroll
  for (int i = 0; i < 16; ++i) sume[i] = 0.0f;

  // wave wv owns col-tiles wv*8 .. wv*8+7 (256 cols); ping-pong Ba/Bb.
  const lx2* Bw = reinterpret_cast<const lx2*>(bsw) + (size_t)wv * 4096 + lane;
  lx2 Ba[8], Bb[8];
#pragma unroll
  for (int p = 0; p < 8; ++p) Ba[p] = Bw[p * 64];

#define ACC_EXP(Bx)                                                          \
  {                                                                          \
    f32x16 acc0, acc1;                                                       \
    _Pragma("unroll") for (int i = 0; i < 16; ++i) {                         \
      acc0[i] = 0.0f;                                                        \
      acc1[i] = 0.0f;                                                        \
    }                                                                        \
    __builtin_amdgcn_s_setprio(1);                                           \
    _Pragma("unroll") for (int p = 0; p < 8; ++p) {                          \
      acc0 = __builtin_amdgcn_mfma_f32_32x32x16_fp8_fp8(A[p].x, Bx[p].x,     \
                                                        acc0, 0, 0, 0);      \
      acc1 = __builtin_amdgcn_mfma_f32_32x32x16_fp8_fp8(A[p].y, Bx[p].y,     \
                                                        acc1, 0, 0, 0);      \
    }                                                                        \
    __builtin_amdgcn_s_setprio(0);                                           \
    _Pragma("unroll") for (int i = 0; i < 16; ++i)                           \
        sume[i] += __expf(fminf(acc0[i] + acc1[i], 40.0f)); /* no inf */     \
  }

#pragma unroll
  for (int tt = 0; tt < 4; ++tt) {
    {  // prefetch tile 2*tt+1 while tile 2*tt computes
      const lx2* Bt = Bw + (2 * tt + 1) * 512;
#pragma unroll
      for (int p = 0; p < 8; ++p) Bb[p] = Bt[p * 64];
    }
    ACC_EXP(Ba);
    if (tt < 3) {  // prefetch tile 2*tt+2 while tile 2*tt+1 computes
      const lx2* Bt = Bw + (2 * tt + 2) * 512;
#pragma unroll
      for (int p = 0; p < 8; ++p) Ba[p] = Bt[p * 64];
    }
    ACC_EXP(Bb);
  }
#undef ACC_EXP

  // ---- reduce sumexp over the wave's 256 cols ----
#pragma unroll
  for (int i = 0; i < 16; ++i) {
    float v = sume[i];
#pragma unroll
    for (int o = 1; o < 32; o <<= 1) v += __shfl_xor(v, o, 64);
    sume[i] = v;
  }
  if ((lane & 31) == 0) {
#pragma unroll
    for (int i = 0; i < 16; ++i)
      rowtot[wv][(i & 3) + 8 * (i >> 2) + 4 * hl] = sume[i];
  }
  __syncthreads();

  // ---- per-row epilogue: self-column swap (exact fp32) + log ----
  if (tid < 32) {
    const int r = blockIdx.x * 32 + tid;
    const float se0 = rowtot[0][tid] + rowtot[1][tid] + rowtot[2][tid] +
                      rowtot[3][tid];
    const float uu = uuA[r], uc = ucA[r], cc = ccv[r / M_UTT];
    const float w = wp[0];
    const float Mf = (float)M_UTT;
    const float ue = (Mf * uc - uu) * (1.0f / (Mf - 1.0f));
    const float ee = (Mf * Mf * cc - 2.0f * Mf * uc + uu) *
                     (1.0f / ((Mf - 1.0f) * (Mf - 1.0f)));
    const float sself = w * ue * rsqrtf(fmaxf(uu * ee, 1e-20f));
    const float sown = w * uc * rsqrtf(fmaxf(uu * cc, 1e-20f));
    const float se = fmaxf(
        se0 + __expf(fminf(sself, 40.f)) - __expf(fminf(sown, 40.f)), 1e-10f);
    float v = __logf(se) - sself;  // LSE - target logit (b cancels)
#pragma unroll
    for (int o = 1; o < 32; o <<= 1) v += __shfl_xor(v, o, 64);
    if (tid == 0) atomicAdd(out, v);
  }
}

extern "C" void kernel_launch(void* const* d_in, const int* in_sizes, int n_in,
                              void* d_out, int out_size, void* d_ws, size_t ws_size,
                              hipStream_t stream) {
  const float* inp = (const float*)d_in[0];
  const float* wp  = (const float*)d_in[1];
  // d_in[2] (b) cancels in LSE - sim_self.
  float* out = (float*)d_out;

  unsigned char* bsw = (unsigned char*)d_ws;                      // 256 KB fp8 B-frags
  int4* Ag   = (int4*)((char*)d_ws + 256 * 1024);                 // 5 MB fp8 A-frags
  float* uuA = (float*)((char*)d_ws + 256 * 1024 + 5 * 1024 * 1024);  // 80 KB
  float* ucA = uuA + (size_t)N_SPK * M_UTT;                       // 80 KB
  float* ccv = ucA + (size_t)N_SPK * M_UTT;                       // 4 KB

  ge2e_prep<<<N_SPK / 4, 256, 0, stream>>>(inp, wp, (unsigned int*)bsw, Ag,
                                           uuA, ucA, ccv, out);
  ge2e_main<<<(N_SPK * M_UTT) / 32, 256, 0, stream>>>(Ag, bsw, wp, uuA, ucA,
                                                      ccv, out);
}

// Round 2
// 95.172 us; speedup vs baseline: 1.1347x; 1.1347x over previous
//
#include <hip/hip_runtime.h>
#include <hip/hip_fp8.h>

// GE2E loss, fp8-MFMA v6 = v4 structure + ping-pong B prefetch in main.
//   prep (256 blocks, 4 speakers/block, 1 wave each): centroid c (fp32 c_raw),
//     cc=||c||^2, c_hat -> fp8 e4m3 pre-swizzled in 32x32x16 fp8 B-frag order.
//     Zeroes out. (v4 prep, unchanged — v5's heavy prep regressed.)
//   main (640 blocks, 4 waves, natural VGPR ~140 -> 3 waves/SIMD): 32 rows x
//     1024 cols. Staging: float4 loads, exact fp32 uu/uc; s=w*rsqrt(uu) folded
//     into A before fp8 quantization -> MFMA output IS the scaled similarity.
//     Tile loop: fully-unrolled ping-pong (static Ba/Bb register sets, no
//     rotate copies -> compiler emits counted vmcnt, never drains): tile t+1's
//     8 dwordx4 loads issue under tile t's 16 MFMAs + exp chain. Single
//     16-deep MFMA accumulator chain (was acc0+acc1) pays for Bb's +32 VGPRs
//     with -16 acc VGPRs, keeping 3 waves/SIMD without a forced bound.
//     Armor: exp clamped, rsqrt/log floored -> NaN structurally impossible.
//     Self-col swap from exact fp32 scalars. One atomicAdd per block.

#define D_DIM 256
#define N_SPK 1024
#define M_UTT 20

typedef long lx2 __attribute__((ext_vector_type(2)));
typedef float f32x16 __attribute__((ext_vector_type(16)));

__device__ __forceinline__ int pk4_fp8(float x0, float x1, float x2, float x3) {
#if __has_builtin(__builtin_amdgcn_cvt_pk_fp8_f32)
  int v = __builtin_amdgcn_cvt_pk_fp8_f32(x0, x1, 0, false);
  v = __builtin_amdgcn_cvt_pk_fp8_f32(x2, x3, v, true);
  return v;
#else
  union { int i; unsigned char b[4]; } u;
  u.b[0] = __hip_fp8_e4m3(x0).__x;
  u.b[1] = __hip_fp8_e4m3(x1).__x;
  u.b[2] = __hip_fp8_e4m3(x2).__x;
  u.b[3] = __hip_fp8_e4m3(x3).__x;
  return u.i;
#endif
}

// ---------------- Kernel A: centroid prep (1 wave per speaker) ----------------
__global__ __launch_bounds__(256) void ge2e_prep(
    const float* __restrict__ inp, unsigned int* __restrict__ bsw32,
    float* __restrict__ c_raw, float* __restrict__ ccv,
    float* __restrict__ out) {
  const int tid = threadIdx.x, lane = tid & 63, wv = tid >> 6;
  const int s = blockIdx.x * 4 + wv;  // speaker; lane owns dims 4*lane..+3
  if (blockIdx.x == 0 && tid == 0) out[0] = 0.0f;

  const float4* up =
      reinterpret_cast<const float4*>(inp + (size_t)s * (M_UTT * D_DIM)) + lane;
  float4 a = make_float4(0.f, 0.f, 0.f, 0.f);
#pragma unroll
  for (int m = 0; m < M_UTT; ++m) {
    const float4 f = up[m * (D_DIM / 4)];
    a.x += f.x; a.y += f.y; a.z += f.z; a.w += f.w;
  }
  const float inv = 1.0f / (float)M_UTT;
  const float4 c = make_float4(a.x * inv, a.y * inv, a.z * inv, a.w * inv);
  reinterpret_cast<float4*>(c_raw + (size_t)s * D_DIM)[lane] = c;

  float cc = c.x * c.x + c.y * c.y + c.z * c.z + c.w * c.w;
#pragma unroll
  for (int o = 1; o < 64; o <<= 1) cc += __shfl_xor(cc, o, 64);
  if (lane == 0) ccv[s] = cc;

  const float r = rsqrtf(fmaxf(cc, 1e-20f));
  const int q = pk4_fp8(c.x * r, c.y * r, c.z * r, c.w * r);
  // B-frag: lane l holds B[n=l&31][k=(l>>5)*8+j]; mem [tile*8+p][64][16B].
  // d = 4*lane: p=lane>>3, sub=(lane>>2)&1, half=(lane>>1)&1, j0=(lane&1)*4.
  const int t = s >> 5, n5 = s & 31;
  const int p = lane >> 3, sub = (lane >> 2) & 1;
  const int half = (lane >> 1) & 1, jb = (lane & 1) * 4;
  bsw32[((((t * 8 + p) * 64) + half * 32 + n5) * 16 + sub * 8 + jb) >> 2] =
      (unsigned int)q;
}

// ---------------- Kernel B: fp8 MFMA GEMM + fused sumexp ----------------
__global__ __launch_bounds__(256) void ge2e_main(
    const float* __restrict__ inp, const float* __restrict__ wp,
    const unsigned char* __restrict__ bsw, const float* __restrict__ c_raw,
    const float* __restrict__ ccv, float* __restrict__ out) {
  __shared__ __align__(16) unsigned char lA[32 * D_DIM];  // 8 KB, A-frag order
  __shared__ float uuL[32], ucL[32], ccL[32];
  __shared__ float rowtot[4][32];
  const int tid = threadIdx.x;
  const int r0 = blockIdx.x * 32;
  const float w = wp[0];

  // ---- staging: 8 threads per row; fold s=w/||u|| into fp8 A-frags ----
  {
    const int m = tid >> 3, seg = tid & 7;
    const int r = r0 + m, nr = r / M_UTT;
    const float4* urow =
        reinterpret_cast<const float4*>(inp + (size_t)r * D_DIM + seg * 32);
    const float4* crow =
        reinterpret_cast<const float4*>(c_raw + (size_t)nr * D_DIM + seg * 32);
    float4 uf[8];
    float uu = 0.f, uc = 0.f;
#pragma unroll
    for (int q = 0; q < 8; ++q) {
      uf[q] = urow[q];
      const float4 cf = crow[q];
      uu += uf[q].x * uf[q].x + uf[q].y * uf[q].y + uf[q].z * uf[q].z +
            uf[q].w * uf[q].w;
      uc += uf[q].x * cf.x + uf[q].y * cf.y + uf[q].z * cf.z + uf[q].w * cf.w;
    }
#pragma unroll
    for (int o = 1; o < 8; o <<= 1) {
      uu += __shfl_xor(uu, o, 64);
      uc += __shfl_xor(uc, o, 64);
    }
    const float s = w * rsqrtf(fmaxf(uu, 1e-20f));
    // A-frag: lane l holds A[m=l&31][k=(l>>5)*8+j]; mem [kspair][lane][sub*8+j]
    int4 ch0, ch1;
    ch0.x = pk4_fp8(s * uf[0].x, s * uf[0].y, s * uf[0].z, s * uf[0].w); // k0-3
    ch0.y = pk4_fp8(s * uf[1].x, s * uf[1].y, s * uf[1].z, s * uf[1].w); // k4-7
    ch0.z = pk4_fp8(s * uf[4].x, s * uf[4].y, s * uf[4].z, s * uf[4].w); // k16-19
    ch0.w = pk4_fp8(s * uf[5].x, s * uf[5].y, s * uf[5].z, s * uf[5].w); // k20-23
    ch1.x = pk4_fp8(s * uf[2].x, s * uf[2].y, s * uf[2].z, s * uf[2].w); // k8-11
    ch1.y = pk4_fp8(s * uf[3].x, s * uf[3].y, s * uf[3].z, s * uf[3].w); // k12-15
    ch1.z = pk4_fp8(s * uf[6].x, s * uf[6].y, s * uf[6].z, s * uf[6].w); // k24-27
    ch1.w = pk4_fp8(s * uf[7].x, s * uf[7].y, s * uf[7].z, s * uf[7].w); // k28-31
    reinterpret_cast<int4*>(lA)[seg * 64 + m] = ch0;       // half 0 (lanes <32)
    reinterpret_cast<int4*>(lA)[seg * 64 + m + 32] = ch1;  // half 1 (lanes >=32)
    if (seg == 0) {
      uuL[m] = uu;
      ucL[m] = uc;
      ccL[m] = ccv[nr];
    }
  }
  __syncthreads();

  const int lane = tid & 63, wv = tid >> 6, hl = lane >> 5;
  lx2 A[8];
  const lx2* lAv = reinterpret_cast<const lx2*>(lA);
#pragma unroll
  for (int p = 0; p < 8; ++p) A[p] = lAv[p * 64 + lane];

  float sume[16];
#pragma unroll
  for (int i = 0; i < 16; ++i) sume[i] = 0.0f;

  // wave wv owns col-tiles wv*8 .. wv*8+7 (256 cols); ping-pong Ba/Bb so the
  // next tile's 8 dwordx4 loads stay in flight under this tile's MFMA+exp
  // (counted vmcnt, no drain — static register sets, no rotate copies).
  const lx2* Bw = reinterpret_cast<const lx2*>(bsw) + (size_t)wv * 4096 + lane;
  lx2 Ba[8], Bb[8];
#pragma unroll
  for (int p = 0; p < 8; ++p) Ba[p] = Bw[p * 64];

#define ACC_EXP(Bx)                                                          \
  {                                                                          \
    f32x16 acc;                                                              \
    _Pragma("unroll") for (int i = 0; i < 16; ++i) acc[i] = 0.0f;            \
    _Pragma("unroll") for (int p = 0; p < 8; ++p) {                          \
      acc = __builtin_amdgcn_mfma_f32_32x32x16_fp8_fp8(A[p].x, Bx[p].x, acc, \
                                                       0, 0, 0);             \
      acc = __builtin_amdgcn_mfma_f32_32x32x16_fp8_fp8(A[p].y, Bx[p].y, acc, \
                                                       0, 0, 0);             \
    }                                                                        \
    _Pragma("unroll") for (int i = 0; i < 16; ++i)                           \
        sume[i] += __expf(fminf(acc[i], 40.0f)); /* armor: no inf */         \
  }

#pragma unroll
  for (int tt = 0; tt < 4; ++tt) {
    {  // prefetch tile 2*tt+1 while tile 2*tt computes
      const lx2* Bt = Bw + (2 * tt + 1) * 512;
#pragma unroll
      for (int p = 0; p < 8; ++p) Bb[p] = Bt[p * 64];
    }
    ACC_EXP(Ba);
    if (tt < 3) {  // prefetch tile 2*tt+2 while tile 2*tt+1 computes
      const lx2* Bt = Bw + (2 * tt + 2) * 512;
#pragma unroll
      for (int p = 0; p < 8; ++p) Ba[p] = Bt[p * 64];
    }
    ACC_EXP(Bb);
  }
#undef ACC_EXP

  // ---- reduce sumexp over the wave's 256 cols ----
#pragma unroll
  for (int i = 0; i < 16; ++i) {
    float v = sume[i];
#pragma unroll
    for (int o = 1; o < 32; o <<= 1) v += __shfl_xor(v, o, 64);
    sume[i] = v;
  }
  if ((lane & 31) == 0) {
#pragma unroll
    for (int i = 0; i < 16; ++i)
      rowtot[wv][(i & 3) + 8 * (i >> 2) + 4 * hl] = sume[i];
  }
  __syncthreads();

  // ---- per-row epilogue: self-column swap (exact fp32) + log ----
  if (tid < 32) {
    const float se0 = rowtot[0][tid] + rowtot[1][tid] + rowtot[2][tid] +
                      rowtot[3][tid];
    const float uu = uuL[tid], uc = ucL[tid], cc = ccL[tid];
    const float Mf = (float)M_UTT;
    const float ue = (Mf * uc - uu) * (1.0f / (Mf - 1.0f));
    const float ee = (Mf * Mf * cc - 2.0f * Mf * uc + uu) *
                     (1.0f / ((Mf - 1.0f) * (Mf - 1.0f)));
    const float sself = w * ue * rsqrtf(fmaxf(uu * ee, 1e-20f));
    const float sown = w * uc * rsqrtf(fmaxf(uu * cc, 1e-20f));
    const float se = fmaxf(
        se0 + __expf(fminf(sself, 40.f)) - __expf(fminf(sown, 40.f)), 1e-10f);
    float v = __logf(se) - sself;  // LSE - target logit (b cancels)
#pragma unroll
    for (int o = 1; o < 32; o <<= 1) v += __shfl_xor(v, o, 64);
    if (tid == 0) atomicAdd(out, v);
  }
}

extern "C" void kernel_launch(void* const* d_in, const int* in_sizes, int n_in,
                              void* d_out, int out_size, void* d_ws, size_t ws_size,
                              hipStream_t stream) {
  const float* inp = (const float*)d_in[0];
  const float* wp  = (const float*)d_in[1];
  // d_in[2] (b) cancels in LSE - sim_self.
  float* out = (float*)d_out;

  unsigned char* bsw = (unsigned char*)d_ws;            // 256 KB fp8 B-frags
  float* c_raw = (float*)((char*)d_ws + 256 * 1024);    // 1 MB
  float* ccv   = c_raw + (size_t)N_SPK * D_DIM;         // 4 KB

  ge2e_prep<<<N_SPK / 4, 256, 0, stream>>>(inp, (unsigned int*)bsw, c_raw, ccv,
                                           out);
  ge2e_main<<<(N_SPK * M_UTT) / 32, 256, 0, stream>>>(inp, wp, bsw, c_raw, ccv,
                                                      out);
}

// Round 3
// 90.703 us; speedup vs baseline: 1.1906x; 1.0493x over previous
//
#include <hip/hip_runtime.h>
#include <hip/hip_fp8.h>

// GE2E loss, fp8-MFMA v7 == v4 (verified-best revert; 89.8/91.1 us over two
// sessions). v5 (prep-heavy restructure) and v6 (ping-pong B prefetch) both
// measured neutral-to-worse after clock normalization: the v4 tile loop is
// issue-bound, not latency-bound (3 waves/SIMD x ~550 cyc issue per tile-round
// vs ~250 cyc L2 latency -> TLP already hides B loads; prefetch buys nothing).
//
// Measured-region budget (rocprof, two sessions): ~44 us harness 256 MiB
// workspace re-poison fill at 76-80% HBM peak (untouchable), ~35-40 us harness
// reset dispatch train (~14 dispatches/iter, untouchable), ~7-10 us these two
// kernels vs ~5.5 us arithmetic floor (2x 20 MB input reads, 327k MFMAs ~1 us,
// 21M exps ~0.6 us). Remaining controllable headroom <= ~3%.
//
//   prep (256 blocks, 4 speakers/block, 1 wave each): centroid c (fp32 c_raw),
//     cc=||c||^2, c_hat -> fp8 e4m3 pre-swizzled in 32x32x16 fp8 B-frag order.
//     Zeroes out.
//   main (640 blocks, 4 waves, natural VGPR ~140 -> 3 waves/SIMD -> all 640
//     resident in one scheduling round): 32 rows x 1024 cols. Staging: float4
//     loads, exact fp32 uu/uc; s=w*rsqrt(uu) folded into A before fp8
//     quantization -> MFMA output IS the scaled similarity (b cancels).
//     Per wave: 8 col-tiles of 32; 8 dwordx4 B loads + 16 MFMAs (2 indep
//     8-chains) + 16 exp-acc per tile. No register-rotate pipeline (the
//     copies forced vmcnt drains; TLP at 12 waves/CU hides latency instead).
//     Armor: exp clamped, rsqrt/log floored -> NaN structurally impossible.
//     Self-col swap from exact fp32 scalars. One atomicAdd per block.

#define D_DIM 256
#define N_SPK 1024
#define M_UTT 20

typedef long lx2 __attribute__((ext_vector_type(2)));
typedef float f32x16 __attribute__((ext_vector_type(16)));

__device__ __forceinline__ int pk4_fp8(float x0, float x1, float x2, float x3) {
#if __has_builtin(__builtin_amdgcn_cvt_pk_fp8_f32)
  int v = __builtin_amdgcn_cvt_pk_fp8_f32(x0, x1, 0, false);
  v = __builtin_amdgcn_cvt_pk_fp8_f32(x2, x3, v, true);
  return v;
#else
  union { int i; unsigned char b[4]; } u;
  u.b[0] = __hip_fp8_e4m3(x0).__x;
  u.b[1] = __hip_fp8_e4m3(x1).__x;
  u.b[2] = __hip_fp8_e4m3(x2).__x;
  u.b[3] = __hip_fp8_e4m3(x3).__x;
  return u.i;
#endif
}

// ---------------- Kernel A: centroid prep (1 wave per speaker) ----------------
__global__ __launch_bounds__(256) void ge2e_prep(
    const float* __restrict__ inp, unsigned int* __restrict__ bsw32,
    float* __restrict__ c_raw, float* __restrict__ ccv,
    float* __restrict__ out) {
  const int tid = threadIdx.x, lane = tid & 63, wv = tid >> 6;
  const int s = blockIdx.x * 4 + wv;  // speaker; lane owns dims 4*lane..+3
  if (blockIdx.x == 0 && tid == 0) out[0] = 0.0f;

  const float4* up =
      reinterpret_cast<const float4*>(inp + (size_t)s * (M_UTT * D_DIM)) + lane;
  float4 a = make_float4(0.f, 0.f, 0.f, 0.f);
#pragma unroll
  for (int m = 0; m < M_UTT; ++m) {
    const float4 f = up[m * (D_DIM / 4)];
    a.x += f.x; a.y += f.y; a.z += f.z; a.w += f.w;
  }
  const float inv = 1.0f / (float)M_UTT;
  const float4 c = make_float4(a.x * inv, a.y * inv, a.z * inv, a.w * inv);
  reinterpret_cast<float4*>(c_raw + (size_t)s * D_DIM)[lane] = c;

  float cc = c.x * c.x + c.y * c.y + c.z * c.z + c.w * c.w;
#pragma unroll
  for (int o = 1; o < 64; o <<= 1) cc += __shfl_xor(cc, o, 64);
  if (lane == 0) ccv[s] = cc;

  const float r = rsqrtf(fmaxf(cc, 1e-20f));
  const int q = pk4_fp8(c.x * r, c.y * r, c.z * r, c.w * r);
  // B-frag: lane l holds B[n=l&31][k=(l>>5)*8+j]; mem [tile*8+p][64][16B].
  // d = 4*lane: p=lane>>3, sub=(lane>>2)&1, half=(lane>>1)&1, j0=(lane&1)*4.
  const int t = s >> 5, n5 = s & 31;
  const int p = lane >> 3, sub = (lane >> 2) & 1;
  const int half = (lane >> 1) & 1, jb = (lane & 1) * 4;
  bsw32[((((t * 8 + p) * 64) + half * 32 + n5) * 16 + sub * 8 + jb) >> 2] =
      (unsigned int)q;
}

// ---------------- Kernel B: fp8 MFMA GEMM + fused sumexp ----------------
__global__ __launch_bounds__(256) void ge2e_main(
    const float* __restrict__ inp, const float* __restrict__ wp,
    const unsigned char* __restrict__ bsw, const float* __restrict__ c_raw,
    const float* __restrict__ ccv, float* __restrict__ out) {
  __shared__ __align__(16) unsigned char lA[32 * D_DIM];  // 8 KB, A-frag order
  __shared__ float uuL[32], ucL[32], ccL[32];
  __shared__ float rowtot[4][32];
  const int tid = threadIdx.x;
  const int r0 = blockIdx.x * 32;
  const float w = wp[0];

  // ---- staging: 8 threads per row; fold s=w/||u|| into fp8 A-frags ----
  {
    const int m = tid >> 3, seg = tid & 7;
    const int r = r0 + m, nr = r / M_UTT;
    const float4* urow =
        reinterpret_cast<const float4*>(inp + (size_t)r * D_DIM + seg * 32);
    const float4* crow =
        reinterpret_cast<const float4*>(c_raw + (size_t)nr * D_DIM + seg * 32);
    float4 uf[8];
    float uu = 0.f, uc = 0.f;
#pragma unroll
    for (int q = 0; q < 8; ++q) {
      uf[q] = urow[q];
      const float4 cf = crow[q];
      uu += uf[q].x * uf[q].x + uf[q].y * uf[q].y + uf[q].z * uf[q].z +
            uf[q].w * uf[q].w;
      uc += uf[q].x * cf.x + uf[q].y * cf.y + uf[q].z * cf.z + uf[q].w * cf.w;
    }
#pragma unroll
    for (int o = 1; o < 8; o <<= 1) {
      uu += __shfl_xor(uu, o, 64);
      uc += __shfl_xor(uc, o, 64);
    }
    const float s = w * rsqrtf(fmaxf(uu, 1e-20f));
    // A-frag: lane l holds A[m=l&31][k=(l>>5)*8+j]; mem [kspair][lane][sub*8+j]
    int4 ch0, ch1;
    ch0.x = pk4_fp8(s * uf[0].x, s * uf[0].y, s * uf[0].z, s * uf[0].w); // k0-3
    ch0.y = pk4_fp8(s * uf[1].x, s * uf[1].y, s * uf[1].z, s * uf[1].w); // k4-7
    ch0.z = pk4_fp8(s * uf[4].x, s * uf[4].y, s * uf[4].z, s * uf[4].w); // k16-19
    ch0.w = pk4_fp8(s * uf[5].x, s * uf[5].y, s * uf[5].z, s * uf[5].w); // k20-23
    ch1.x = pk4_fp8(s * uf[2].x, s * uf[2].y, s * uf[2].z, s * uf[2].w); // k8-11
    ch1.y = pk4_fp8(s * uf[3].x, s * uf[3].y, s * uf[3].z, s * uf[3].w); // k12-15
    ch1.z = pk4_fp8(s * uf[6].x, s * uf[6].y, s * uf[6].z, s * uf[6].w); // k24-27
    ch1.w = pk4_fp8(s * uf[7].x, s * uf[7].y, s * uf[7].z, s * uf[7].w); // k28-31
    reinterpret_cast<int4*>(lA)[seg * 64 + m] = ch0;       // half 0 (lanes <32)
    reinterpret_cast<int4*>(lA)[seg * 64 + m + 32] = ch1;  // half 1 (lanes >=32)
    if (seg == 0) {
      uuL[m] = uu;
      ucL[m] = uc;
      ccL[m] = ccv[nr];
    }
  }
  __syncthreads();

  const int lane = tid & 63, wv = tid >> 6, hl = lane >> 5;
  lx2 A[8];
  const lx2* lAv = reinterpret_cast<const lx2*>(lA);
#pragma unroll
  for (int p = 0; p < 8; ++p) A[p] = lAv[p * 64 + lane];

  float sume[16];
#pragma unroll
  for (int i = 0; i < 16; ++i) sume[i] = 0.0f;

  const lx2* Bv = reinterpret_cast<const lx2*>(bsw);
#pragma unroll 1
  for (int t = 0; t < 8; ++t) {
    const lx2* Bt = Bv + (size_t)(wv * 8 + t) * 512 + lane;
    lx2 B[8];
#pragma unroll
    for (int p = 0; p < 8; ++p) B[p] = Bt[p * 64];
    f32x16 acc0, acc1;
#pragma unroll
    for (int i = 0; i < 16; ++i) { acc0[i] = 0.0f; acc1[i] = 0.0f; }
#pragma unroll
    for (int p = 0; p < 8; ++p) {
      acc0 = __builtin_amdgcn_mfma_f32_32x32x16_fp8_fp8(A[p].x, B[p].x, acc0,
                                                        0, 0, 0);
      acc1 = __builtin_amdgcn_mfma_f32_32x32x16_fp8_fp8(A[p].y, B[p].y, acc1,
                                                        0, 0, 0);
    }
#pragma unroll
    for (int i = 0; i < 16; ++i)
      sume[i] += __expf(fminf(acc0[i] + acc1[i], 40.0f));  // armor: no inf
  }

  // ---- reduce sumexp over the wave's 256 cols ----
#pragma unroll
  for (int i = 0; i < 16; ++i) {
    float v = sume[i];
#pragma unroll
    for (int o = 1; o < 32; o <<= 1) v += __shfl_xor(v, o, 64);
    sume[i] = v;
  }
  if ((lane & 31) == 0) {
#pragma unroll
    for (int i = 0; i < 16; ++i)
      rowtot[wv][(i & 3) + 8 * (i >> 2) + 4 * hl] = sume[i];
  }
  __syncthreads();

  // ---- per-row epilogue: self-column swap (exact fp32) + log ----
  if (tid < 32) {
    const float se0 = rowtot[0][tid] + rowtot[1][tid] + rowtot[2][tid] +
                      rowtot[3][tid];
    const float uu = uuL[tid], uc = ucL[tid], cc = ccL[tid];
    const float Mf = (float)M_UTT;
    const float ue = (Mf * uc - uu) * (1.0f / (Mf - 1.0f));
    const float ee = (Mf * Mf * cc - 2.0f * Mf * uc + uu) *
                     (1.0f / ((Mf - 1.0f) * (Mf - 1.0f)));
    const float sself = w * ue * rsqrtf(fmaxf(uu * ee, 1e-20f));
    const float sown = w * uc * rsqrtf(fmaxf(uu * cc, 1e-20f));
    const float se = fmaxf(
        se0 + __expf(fminf(sself, 40.f)) - __expf(fminf(sown, 40.f)), 1e-10f);
    float v = __logf(se) - sself;  // LSE - target logit (b cancels)
#pragma unroll
    for (int o = 1; o < 32; o <<= 1) v += __shfl_xor(v, o, 64);
    if (tid == 0) atomicAdd(out, v);
  }
}

extern "C" void kernel_launch(void* const* d_in, const int* in_sizes, int n_in,
                              void* d_out, int out_size, void* d_ws, size_t ws_size,
                              hipStream_t stream) {
  const float* inp = (const float*)d_in[0];
  const float* wp  = (const float*)d_in[1];
  // d_in[2] (b) cancels in LSE - sim_self.
  float* out = (float*)d_out;

  unsigned char* bsw = (unsigned char*)d_ws;            // 256 KB fp8 B-frags
  float* c_raw = (float*)((char*)d_ws + 256 * 1024);    // 1 MB
  float* ccv   = c_raw + (size_t)N_SPK * D_DIM;         // 4 KB

  ge2e_prep<<<N_SPK / 4, 256, 0, stream>>>(inp, (unsigned int*)bsw, c_raw, ccv,
                                           out);
  ge2e_main<<<(N_SPK * M_UTT) / 32, 256, 0, stream>>>(inp, wp, bsw, c_raw, ccv,
                                                      out);
}